// Round 14
// baseline (296.967 us; speedup 1.0000x reference)
//
#include <hip/hip_runtime.h>
#include <hip/hip_bf16.h>
#include <math.h>

// ---------------------------------------------------------------------------
// GAT 2-layer forward.  N=100000 nodes, E=1.6M edges, self-loops in CSR.
// L1: 128 -> H=8,C=16 ; L2: 128 -> H=1,C=64.
// GEMMs on MFMA 16x16x32 bf16, split-bf16 (hi+lo, 3 mfma) ~f32 accuracy.
// CSR with zero global atomics (two-level LDS bucketing).
// agg_pass: uint4 row gathers, sentinel-node padding (no guards), exp2 with
// log2e-prescaled scores, den inline.  No score_pass.
// ---------------------------------------------------------------------------

#define TPB 256
#define SCAN_B 256
#define LOG2E 1.44269504088896f

typedef unsigned int uint;
typedef unsigned short ushort;
typedef short bf16x8 __attribute__((ext_vector_type(8)));
typedef float f32x4 __attribute__((ext_vector_type(4)));

__device__ __forceinline__ ushort bfr(float x) {          // f32 -> bf16 RTNE
    uint u = __float_as_uint(x);
    return (ushort)((u + 0x7fffu + ((u >> 16) & 1u)) >> 16);
}
__device__ __forceinline__ float ubf(ushort s) {          // bf16 -> f32
    return __uint_as_float((uint)s << 16);
}

// Detect whether edge_index is int64 (odd 32-bit words all zero) or int32.
__global__ void detect_idx64(const unsigned* __restrict__ p, int* __restrict__ flag) {
    unsigned v = p[threadIdx.x * 2 + 1];
    unsigned long long b = __ballot(v != 0u);
    if (threadIdx.x == 0) *flag = (b == 0ull) ? 1 : 0;
}

// sentinel scores for the padding node Nn: exp2 -> 0
__global__ void set_sentinels(float* __restrict__ asrc1, float* __restrict__ asrc2, int Nn) {
    int t = threadIdx.x;
    if (t < 8) asrc1[(size_t)8 * Nn + t] = -1e30f;
    if (t == 8) asrc2[Nn] = -1e30f;
}

// W[k][col] f32 -> frag-ready hi/lo bf16 at [(k/8)*NCOL + col][k%8]
__global__ void convert_W(const float* __restrict__ W, ushort* __restrict__ Wfh,
                          ushort* __restrict__ Wfl, int total, int NCOL) {
    int i = blockIdx.x * TPB + threadIdx.x;
    if (i >= total) return;
    int k = i / NCOL, col = i % NCOL;
    float w = W[i];
    ushort hh = bfr(w);
    float lo = w - ubf(hh);
    int o = ((k >> 3) * NCOL + col) * 8 + (k & 7);
    Wfh[o] = hh;
    Wfl[o] = bfr(lo);
}

// ---------------- CSR build: two-level bucketing, no global atomics ---------
__global__ __launch_bounds__(TPB) void hist_coarse(
    const int* __restrict__ ei, const int* __restrict__ shiftp, int E, int nb1,
    int* __restrict__ bh)
{
    __shared__ int hist[512];
    for (int i = threadIdx.x; i < nb1; i += TPB) hist[i] = 0;
    __syncthreads();
    const int sh = *shiftp;
    const int e0 = blockIdx.x * (TPB * 4) + threadIdx.x;
#pragma unroll
    for (int k = 0; k < 4; ++k) {
        int e = e0 + k * TPB;
        if (e < E) {
            int d = ei[((size_t)E + e) << sh];
            atomicAdd(&hist[d >> 8], 1);          // LDS atomic
        }
    }
    __syncthreads();
    for (int i = threadIdx.x; i < nb1; i += TPB)
        bh[(size_t)blockIdx.x * nb1 + i] = hist[i];
}

__global__ __launch_bounds__(TPB) void scan_bh(
    int* __restrict__ bh, int gbe, int nb1, int* __restrict__ btot)
{
    __shared__ int sm[TPB];
    const int bin = blockIdx.x;
    int running = 0;
    for (int c0 = 0; c0 < gbe; c0 += TPB) {
        int idx = c0 + threadIdx.x;
        int v = (idx < gbe) ? bh[(size_t)idx * nb1 + bin] : 0;
        sm[threadIdx.x] = v;
        __syncthreads();
        for (int off = 1; off < TPB; off <<= 1) {
            int t = (threadIdx.x >= off) ? sm[threadIdx.x - off] : 0;
            __syncthreads();
            sm[threadIdx.x] += t;
            __syncthreads();
        }
        if (idx < gbe) bh[(size_t)idx * nb1 + bin] = running + sm[threadIdx.x] - v;
        int ctot = sm[TPB - 1];
        __syncthreads();
        running += ctot;
    }
    if (threadIdx.x == 0) btot[bin] = running;
}

__global__ void scan_btot(const int* __restrict__ btot, int* __restrict__ bstart, int nb) {
    __shared__ int sm[512];
    int v = (threadIdx.x < nb) ? btot[threadIdx.x] : 0;
    sm[threadIdx.x] = v;
    __syncthreads();
    for (int off = 1; off < 512; off <<= 1) {
        int t = (threadIdx.x >= off) ? sm[threadIdx.x - off] : 0;
        __syncthreads();
        sm[threadIdx.x] += t;
        __syncthreads();
    }
    if (threadIdx.x < nb) bstart[threadIdx.x] = sm[threadIdx.x] - v;
}

__global__ __launch_bounds__(TPB) void scatter_coarse(
    const int* __restrict__ ei, const int* __restrict__ shiftp, int E, int nb1,
    const int* __restrict__ bh, const int* __restrict__ bstart,
    int2* __restrict__ ebuf)
{
    __shared__ int hist[512];
    for (int i = threadIdx.x; i < nb1; i += TPB) hist[i] = 0;
    __syncthreads();
    const int sh = *shiftp;
    const int e0 = blockIdx.x * (TPB * 4) + threadIdx.x;
#pragma unroll
    for (int k = 0; k < 4; ++k) {
        int e = e0 + k * TPB;
        if (e < E) {
            int s = ei[(size_t)e << sh];
            int d = ei[((size_t)E + e) << sh];
            int bin = d >> 8;
            int lr = atomicAdd(&hist[bin], 1);     // LDS atomic
            int pos = bstart[bin] + bh[(size_t)blockIdx.x * nb1 + bin] + lr;
            ebuf[pos] = make_int2(s, d);
        }
    }
}

__global__ __launch_bounds__(TPB) void fine_count(
    const int2* __restrict__ ebuf, const int* __restrict__ bstart,
    const int* __restrict__ btot, int* __restrict__ cnt, int Nn)
{
    __shared__ int hist[TPB];
    hist[threadIdx.x] = 0;
    __syncthreads();
    const int b    = blockIdx.x;
    const int base = bstart[b];
    const int ne   = btot[b];
    const int nb0  = b << 8;
    for (int i = threadIdx.x; i < ne; i += TPB)
        atomicAdd(&hist[ebuf[base + i].y - nb0], 1);   // LDS atomic
    __syncthreads();
    int node = nb0 + threadIdx.x;
    if (node < Nn) cnt[node] = hist[threadIdx.x] + 1;
}

__global__ __launch_bounds__(TPB) void fine_scatter(
    const int2* __restrict__ ebuf, const int* __restrict__ bstart,
    const int* __restrict__ btot, const int* __restrict__ startp,
    int* __restrict__ adj)
{
    __shared__ int hist[TPB];
    hist[threadIdx.x] = 0;
    __syncthreads();
    const int b    = blockIdx.x;
    const int base = bstart[b];
    const int ne   = btot[b];
    const int nb0  = b << 8;
    for (int i = threadIdx.x; i < ne; i += TPB) {
        int2 e = ebuf[base + i];
        int lr = atomicAdd(&hist[e.y - nb0], 1);       // LDS atomic
        adj[startp[e.y] + 1 + lr] = e.x;
    }
}

// ---------------- node-level scan (cnt -> startp, self-loops) ---------------
__global__ void scan_block(const int* __restrict__ cnt, int* __restrict__ excl,
                           int* __restrict__ bsum, int n) {
    __shared__ int sm[SCAN_B];
    int i = blockIdx.x * SCAN_B + threadIdx.x;
    int v = (i < n) ? cnt[i] : 0;
    sm[threadIdx.x] = v;
    __syncthreads();
    for (int off = 1; off < SCAN_B; off <<= 1) {
        int t = (threadIdx.x >= off) ? sm[threadIdx.x - off] : 0;
        __syncthreads();
        sm[threadIdx.x] += t;
        __syncthreads();
    }
    if (i < n) excl[i] = sm[threadIdx.x] - v;
    if (threadIdx.x == SCAN_B - 1) bsum[blockIdx.x] = sm[threadIdx.x];
}

__global__ void scan_bsum(int* __restrict__ bsum, int nb) {   // one block, nb<=512
    __shared__ int sm[512];
    int v = (threadIdx.x < nb) ? bsum[threadIdx.x] : 0;
    sm[threadIdx.x] = v;
    __syncthreads();
    for (int off = 1; off < 512; off <<= 1) {
        int t = (threadIdx.x >= off) ? sm[threadIdx.x - off] : 0;
        __syncthreads();
        sm[threadIdx.x] += t;
        __syncthreads();
    }
    if (threadIdx.x < nb) bsum[threadIdx.x] = sm[threadIdx.x] - v;
}

__global__ void scan_add_self(int* __restrict__ excl, const int* __restrict__ bsum,
                              int* __restrict__ adj, int n) {
    int i = blockIdx.x * SCAN_B + threadIdx.x;
    if (i < n) {
        int s = excl[i] + bsum[blockIdx.x];
        excl[i] = s;          // excl becomes start
        adj[s]  = i;          // self-loop first in row
    }
}

__device__ __forceinline__ float4 f4z() { return make_float4(0.f, 0.f, 0.f, 0.f); }

// ---------------- MFMA GEMM (+ attention-dot epilogue) ----------------------
// asrc/adst written PRE-SCALED by log2(e) so agg_pass can use native exp2.
template<int NCOL, int H, int C>
__global__ __launch_bounds__(TPB) void gemm_att_k(
    const float* __restrict__ X,
    const ushort* __restrict__ Wfh, const ushort* __restrict__ Wfl,
    const float* __restrict__ att_src, const float* __restrict__ att_dst,
    ushort* __restrict__ Hout, float* __restrict__ asrc, float* __restrict__ adst,
    int Nrows)
{
    constexpr int CT  = NCOL / 16;     // col tiles (8 L1, 4 L2)
    constexpr int GRP = C / 16;        // col tiles per head (1 L1, 4 L2)
    constexpr int LSTR = 136;          // LDS row stride (shorts)

    __shared__ ushort Xh[64 * LSTR], Xl[64 * LSTR];

    const int tid  = threadIdx.x;
    const int row0 = blockIdx.x * 64;

    for (int idx = tid; idx < 64 * 32; idx += TPB) {
        int row = idx >> 5, c4 = idx & 31;
        int gr = row0 + row;
        float4 v = (gr < Nrows) ? ((const float4*)(X + (size_t)gr * 128))[c4] : f4z();
        ushort4 hh, ll;
        hh.x = bfr(v.x); hh.y = bfr(v.y); hh.z = bfr(v.z); hh.w = bfr(v.w);
        ll.x = bfr(v.x - ubf(hh.x)); ll.y = bfr(v.y - ubf(hh.y));
        ll.z = bfr(v.z - ubf(hh.z)); ll.w = bfr(v.w - ubf(hh.w));
        *(ushort4*)&Xh[row * LSTR + c4 * 4] = hh;
        *(ushort4*)&Xl[row * LSTR + c4 * 4] = ll;
    }
    __syncthreads();

    const int lane = tid & 63;
    const int wv   = tid >> 6;       // row tile
    const int lr   = lane & 15;      // A row / B,D col within tile
    const int lk   = lane >> 4;      // k subgroup

    f32x4 acc[CT];
#pragma unroll
    for (int ct = 0; ct < CT; ++ct) acc[ct] = (f32x4){0.f, 0.f, 0.f, 0.f};

#pragma unroll
    for (int kt = 0; kt < 4; ++kt) {
        bf16x8 ah = *(bf16x8*)&Xh[(wv * 16 + lr) * LSTR + kt * 32 + lk * 8];
        bf16x8 al = *(bf16x8*)&Xl[(wv * 16 + lr) * LSTR + kt * 32 + lk * 8];
        const int kb = (kt * 4 + lk) * NCOL;
#pragma unroll
        for (int ct = 0; ct < CT; ++ct) {
            bf16x8 bh = *(const bf16x8*)(Wfh + (size_t)(kb + ct * 16 + lr) * 8);
            bf16x8 bl = *(const bf16x8*)(Wfl + (size_t)(kb + ct * 16 + lr) * 8);
            acc[ct] = __builtin_amdgcn_mfma_f32_16x16x32_bf16(ah, bh, acc[ct], 0, 0, 0);
            acc[ct] = __builtin_amdgcn_mfma_f32_16x16x32_bf16(ah, bl, acc[ct], 0, 0, 0);
            acc[ct] = __builtin_amdgcn_mfma_f32_16x16x32_bf16(al, bh, acc[ct], 0, 0, 0);
        }
    }

    // ---- epilogue: h store (bf16) + per-head attention dots ----
    float asv[CT], adv[CT];
#pragma unroll
    for (int ct = 0; ct < CT; ++ct) {
        asv[ct] = att_src[ct * 16 + lr];   // (H,C) contiguous == flat col
        adv[ct] = att_dst[ct * 16 + lr];
    }

#pragma unroll
    for (int r = 0; r < 4; ++r) {
        const int n  = row0 + wv * 16 + lk * 4 + r;
        const bool ok = (n < Nrows);
        if (ok) {
#pragma unroll
            for (int ct = 0; ct < CT; ++ct)
                Hout[(size_t)n * NCOL + ct * 16 + lr] = bfr(acc[ct][r]);
        }
#pragma unroll
        for (int hg = 0; hg < CT / GRP; ++hg) {
            float ps = 0.f, pd = 0.f;
#pragma unroll
            for (int g = 0; g < GRP; ++g) {
                float a = acc[hg * GRP + g][r];
                ps += a * asv[hg * GRP + g];
                pd += a * adv[hg * GRP + g];
            }
#pragma unroll
            for (int s = 1; s < 16; s <<= 1) {
                ps += __shfl_xor(ps, s, 64);
                pd += __shfl_xor(pd, s, 64);
            }
            if (ok && lr == 0) {
                asrc[(size_t)n * H + hg] = ps * LOG2E;
                adst[(size_t)n * H + hg] = pd * LOG2E;
            }
        }
    }
}

// ---------------- fused aggregation (uint4, sentinel, exp2) -----------------
// One wave per node.  lane = (eg, cg): cg = lane%LPR column chunk (uint4 =
// 8 bf16 cols), eg = edge slot.  Out-of-range lanes use sentinel node Nn
// (asrc[Nn] = -1e30 -> pj = 0), so the inner loop has NO guards.
template<int H, int C, bool DOELU>
__global__ __launch_bounds__(TPB) void agg_pass(
    const ushort* __restrict__ Hf, const int* __restrict__ adj,
    const int* __restrict__ cnt, const int* __restrict__ start,
    const float* __restrict__ asrc, const float* __restrict__ adst,
    const float* __restrict__ bias, float* __restrict__ out, int Nn)
{
    constexpr int F   = H * C;
    constexpr int LPR = F / 8;      // lanes per row (16 L1, 8 L2)
    constexpr int EPL = 64 / LPR;   // edges per wave-load (4 L1, 8 L2)
    constexpr int GQ  = 4;          // load-units in flight

    const int lane = threadIdx.x & 63;
    const int d    = blockIdx.x * (TPB / 64) + (threadIdx.x >> 6);
    if (d >= Nn) return;

    const int eg = lane / LPR;
    const int cg = lane % LPR;
    const int hc = (cg * 8) / C;    // head of this lane's columns

    const float adstv = adst[(size_t)d * H + hc];

    float acc[8] = {0.f, 0.f, 0.f, 0.f, 0.f, 0.f, 0.f, 0.f};
    float den = 0.f;

    const int ne = cnt[d];
    const int rs = start[d];

    for (int b = 0; b < ne; b += 64) {
        const int kn = min(64, ne - b);
        int sj = (lane < kn) ? adj[rs + b + lane] : Nn;

        for (int g = 0; g * (GQ * EPL) < kn; ++g) {
            uint4 wv[GQ];
            float av[GQ];
#pragma unroll
            for (int qi = 0; qi < GQ; ++qi) {
                int j  = (g * GQ + qi) * EPL + eg;
                int sv = __shfl(sj, j, 64);
                wv[qi] = *(const uint4*)(Hf + (size_t)sv * F + cg * 8);
                av[qi] = asrc[(size_t)sv * H + hc];
            }
#pragma unroll
            for (int qi = 0; qi < GQ; ++qi) {
                float t = av[qi] + adstv;           // log2-domain score
                t = t > 0.f ? t : 0.2f * t;         // leaky (homogeneous)
                float pj = exp2f(t);                // native v_exp_f32
                den += pj;
                acc[0] += pj * ubf((ushort)(wv[qi].x & 0xffffu));
                acc[1] += pj * ubf((ushort)(wv[qi].x >> 16));
                acc[2] += pj * ubf((ushort)(wv[qi].y & 0xffffu));
                acc[3] += pj * ubf((ushort)(wv[qi].y >> 16));
                acc[4] += pj * ubf((ushort)(wv[qi].z & 0xffffu));
                acc[5] += pj * ubf((ushort)(wv[qi].z >> 16));
                acc[6] += pj * ubf((ushort)(wv[qi].w & 0xffffu));
                acc[7] += pj * ubf((ushort)(wv[qi].w >> 16));
            }
        }
    }

    // fold edge slots (lanes differing in eg share cg / head)
#pragma unroll
    for (int s = LPR; s < 64; s <<= 1) {
        den += __shfl_xor(den, s, 64);
#pragma unroll
        for (int c = 0; c < 8; ++c) acc[c] += __shfl_xor(acc[c], s, 64);
    }

    if (eg == 0) {
        const float invd = 1.0f / (den + 1e-16f);
        float o[8];
#pragma unroll
        for (int c = 0; c < 8; ++c) {
            float t = acc[c] * invd + bias[cg * 8 + c];
            if (DOELU) t = t > 0.f ? t : expm1f(t);
            o[c] = t;
        }
        *(float4*)(out + (size_t)d * F + cg * 8)     = make_float4(o[0], o[1], o[2], o[3]);
        *(float4*)(out + (size_t)d * F + cg * 8 + 4) = make_float4(o[4], o[5], o[6], o[7]);
    }
}

static inline unsigned nblk(long long tot) { return (unsigned)((tot + TPB - 1) / TPB); }

extern "C" void kernel_launch(void* const* d_in, const int* in_sizes, int n_in,
                              void* d_out, int out_size, void* d_ws, size_t ws_size,
                              hipStream_t stream)
{
    const float* x   = (const float*)d_in[0];
    const int*   ei  = (const int*)d_in[1];   // int32 or int64 (detected)
    const float* W1  = (const float*)d_in[2];
    const float* as1 = (const float*)d_in[3];
    const float* ad1 = (const float*)d_in[4];
    const float* b1  = (const float*)d_in[5];
    const float* W2  = (const float*)d_in[6];
    const float* as2 = (const float*)d_in[7];
    const float* ad2 = (const float*)d_in[8];
    const float* b2  = (const float*)d_in[9];
    float* out = (float*)d_out;

    const int Nn  = in_sizes[0] / 128;   // 100000
    const int E   = in_sizes[1] / 2;     // 1600000
    const int ET  = E + Nn;              // edges incl self-loops
    const int NB1 = (Nn + 255) / 256;    // coarse buckets (391)
    const int GBE = (E + 1023) / 1024;   // edge blocks (1563)

    // workspace layout (float units)
    float*  ws    = (float*)d_ws;
    ushort* h1b   = (ushort*)ws;                       // 128*(N+1) bf16 (sentinel row)
    float*  helu  = (float*)(h1b + (size_t)128 * (Nn + 1));  // 128N f32
    float*  asrc2 = helu + (size_t)128 * Nn;           // N+1 (sentinel)
    float*  adst2 = asrc2 + Nn + 1;                    // N
    ushort* w1h   = (ushort*)(adst2 + Nn);             // 16384
    ushort* w1l   = w1h + 16384;                       // 16384
    ushort* w2h   = w1l + 16384;                       // 8192
    ushort* w2l   = w2h + 8192;                        // 8192
    int*    cnt   = (int*)(w2l + 8192);                // N
    int*    startp= cnt + Nn;                          // N
    int*    bsum  = startp + Nn;                       // 512
    int*    adj   = bsum + 512;                        // ET + pad
    int*    bh    = adj + ET + 64;                     // GBE*NB1 (~611K)
    int*    btot  = bh + (size_t)GBE * NB1;            // 512
    int*    bstart= btot + 512;                        // 512
    int*    flag  = bstart + 512;                      // 1 (+pad to even)
    int2*   ebuf  = (int2*)(flag + 3);                 // E int2
    ushort* h2b   = h1b;                               // 64*(N+1) bf16 (L2 reuse)
    // layer-1 attention scores live in d_out (dead before final write)
    float*  asrc1 = out;                               // 8*(N+1)
    float*  adst1 = asrc1 + (size_t)8 * (Nn + 1);      // 8N

    const int NB = (Nn + SCAN_B - 1) / SCAN_B;         // 391 <= 512
    const int GB = (Nn + 63) / 64;                     // gemm blocks (1563)

    detect_idx64<<<1, 64, 0, stream>>>((const unsigned*)ei, flag);
    convert_W<<<64, TPB, 0, stream>>>(W1, w1h, w1l, 128 * 128, 128);
    convert_W<<<32, TPB, 0, stream>>>(W2, w2h, w2l, 128 * 64, 64);
    set_sentinels<<<1, 64, 0, stream>>>(asrc1, asrc2, Nn);

    // ---- CSR build: two-level bucketing, zero global atomics ----
    hist_coarse<<<GBE, TPB, 0, stream>>>(ei, flag, E, NB1, bh);
    scan_bh<<<NB1, TPB, 0, stream>>>(bh, GBE, NB1, btot);
    scan_btot<<<1, 512, 0, stream>>>(btot, bstart, NB1);
    scatter_coarse<<<GBE, TPB, 0, stream>>>(ei, flag, E, NB1, bh, bstart, ebuf);
    fine_count<<<NB1, TPB, 0, stream>>>(ebuf, bstart, btot, cnt, Nn);
    scan_block<<<NB, SCAN_B, 0, stream>>>(cnt, startp, bsum, Nn);
    scan_bsum<<<1, 512, 0, stream>>>(bsum, NB);
    scan_add_self<<<NB, SCAN_B, 0, stream>>>(startp, bsum, adj, Nn);
    fine_scatter<<<NB1, TPB, 0, stream>>>(ebuf, bstart, btot, startp, adj);

    // ---- layer 1 ----
    gemm_att_k<128, 8, 16><<<GB, TPB, 0, stream>>>(
        x, w1h, w1l, as1, ad1, h1b, asrc1, adst1, Nn);
    agg_pass<8, 16, true><<<(Nn + 3) / 4, TPB, 0, stream>>>(
        h1b, adj, cnt, startp, asrc1, adst1, b1, helu, Nn);

    // ---- layer 2 ----
    gemm_att_k<64, 1, 64><<<GB, TPB, 0, stream>>>(
        helu, w2h, w2l, as2, ad2, h2b, asrc2, adst2, Nn);
    agg_pass<1, 64, false><<<(Nn + 3) / 4, TPB, 0, stream>>>(
        h2b, adj, cnt, startp, asrc2, adst2, b2, out, Nn);
}

// Round 15
// 284.093 us; speedup vs baseline: 1.0453x; 1.0453x over previous
//
#include <hip/hip_runtime.h>
#include <hip/hip_bf16.h>
#include <math.h>

// ---------------------------------------------------------------------------
// GAT 2-layer forward.  N=100000 nodes, E=1.6M edges, self-loops in CSR.
// L1: 128 -> H=8,C=16 ; L2: 128 -> H=1,C=64.
// GEMMs on MFMA 16x16x32 bf16, split-bf16 (hi+lo, 3 mfma) ~f32 accuracy.
// CSR with zero global atomics (two-level LDS bucketing).
// agg_pass: R12 uint2 structure + exp2(log2e-prescaled scores) + sentinel
// padding (no guards) + leaky via fmax.  No score_pass.
// ---------------------------------------------------------------------------

#define TPB 256
#define SCAN_B 256
#define LOG2E 1.44269504088896f

typedef unsigned int uint;
typedef unsigned short ushort;
typedef short bf16x8 __attribute__((ext_vector_type(8)));
typedef float f32x4 __attribute__((ext_vector_type(4)));

__device__ __forceinline__ ushort bfr(float x) {          // f32 -> bf16 RTNE
    uint u = __float_as_uint(x);
    return (ushort)((u + 0x7fffu + ((u >> 16) & 1u)) >> 16);
}
__device__ __forceinline__ float ubf(ushort s) {          // bf16 -> f32
    return __uint_as_float((uint)s << 16);
}

// Detect whether edge_index is int64 (odd 32-bit words all zero) or int32.
__global__ void detect_idx64(const unsigned* __restrict__ p, int* __restrict__ flag) {
    unsigned v = p[threadIdx.x * 2 + 1];
    unsigned long long b = __ballot(v != 0u);
    if (threadIdx.x == 0) *flag = (b == 0ull) ? 1 : 0;
}

// sentinel scores for the padding node Nn: exp2 -> 0
__global__ void set_sentinels(float* __restrict__ asrc1, float* __restrict__ asrc2, int Nn) {
    int t = threadIdx.x;
    if (t < 8) asrc1[(size_t)8 * Nn + t] = -1e30f;
    if (t == 8) asrc2[Nn] = -1e30f;
}

// W[k][col] f32 -> frag-ready hi/lo bf16 at [(k/8)*NCOL + col][k%8]
__global__ void convert_W(const float* __restrict__ W, ushort* __restrict__ Wfh,
                          ushort* __restrict__ Wfl, int total, int NCOL) {
    int i = blockIdx.x * TPB + threadIdx.x;
    if (i >= total) return;
    int k = i / NCOL, col = i % NCOL;
    float w = W[i];
    ushort hh = bfr(w);
    float lo = w - ubf(hh);
    int o = ((k >> 3) * NCOL + col) * 8 + (k & 7);
    Wfh[o] = hh;
    Wfl[o] = bfr(lo);
}

// ---------------- CSR build: two-level bucketing, no global atomics ---------
__global__ __launch_bounds__(TPB) void hist_coarse(
    const int* __restrict__ ei, const int* __restrict__ shiftp, int E, int nb1,
    int* __restrict__ bh)
{
    __shared__ int hist[512];
    for (int i = threadIdx.x; i < nb1; i += TPB) hist[i] = 0;
    __syncthreads();
    const int sh = *shiftp;
    const int e0 = blockIdx.x * (TPB * 4) + threadIdx.x;
#pragma unroll
    for (int k = 0; k < 4; ++k) {
        int e = e0 + k * TPB;
        if (e < E) {
            int d = ei[((size_t)E + e) << sh];
            atomicAdd(&hist[d >> 8], 1);          // LDS atomic
        }
    }
    __syncthreads();
    for (int i = threadIdx.x; i < nb1; i += TPB)
        bh[(size_t)blockIdx.x * nb1 + i] = hist[i];
}

__global__ __launch_bounds__(TPB) void scan_bh(
    int* __restrict__ bh, int gbe, int nb1, int* __restrict__ btot)
{
    __shared__ int sm[TPB];
    const int bin = blockIdx.x;
    int running = 0;
    for (int c0 = 0; c0 < gbe; c0 += TPB) {
        int idx = c0 + threadIdx.x;
        int v = (idx < gbe) ? bh[(size_t)idx * nb1 + bin] : 0;
        sm[threadIdx.x] = v;
        __syncthreads();
        for (int off = 1; off < TPB; off <<= 1) {
            int t = (threadIdx.x >= off) ? sm[threadIdx.x - off] : 0;
            __syncthreads();
            sm[threadIdx.x] += t;
            __syncthreads();
        }
        if (idx < gbe) bh[(size_t)idx * nb1 + bin] = running + sm[threadIdx.x] - v;
        int ctot = sm[TPB - 1];
        __syncthreads();
        running += ctot;
    }
    if (threadIdx.x == 0) btot[bin] = running;
}

__global__ void scan_btot(const int* __restrict__ btot, int* __restrict__ bstart, int nb) {
    __shared__ int sm[512];
    int v = (threadIdx.x < nb) ? btot[threadIdx.x] : 0;
    sm[threadIdx.x] = v;
    __syncthreads();
    for (int off = 1; off < 512; off <<= 1) {
        int t = (threadIdx.x >= off) ? sm[threadIdx.x - off] : 0;
        __syncthreads();
        sm[threadIdx.x] += t;
        __syncthreads();
    }
    if (threadIdx.x < nb) bstart[threadIdx.x] = sm[threadIdx.x] - v;
}

__global__ __launch_bounds__(TPB) void scatter_coarse(
    const int* __restrict__ ei, const int* __restrict__ shiftp, int E, int nb1,
    const int* __restrict__ bh, const int* __restrict__ bstart,
    int2* __restrict__ ebuf)
{
    __shared__ int hist[512];
    for (int i = threadIdx.x; i < nb1; i += TPB) hist[i] = 0;
    __syncthreads();
    const int sh = *shiftp;
    const int e0 = blockIdx.x * (TPB * 4) + threadIdx.x;
#pragma unroll
    for (int k = 0; k < 4; ++k) {
        int e = e0 + k * TPB;
        if (e < E) {
            int s = ei[(size_t)e << sh];
            int d = ei[((size_t)E + e) << sh];
            int bin = d >> 8;
            int lr = atomicAdd(&hist[bin], 1);     // LDS atomic
            int pos = bstart[bin] + bh[(size_t)blockIdx.x * nb1 + bin] + lr;
            ebuf[pos] = make_int2(s, d);
        }
    }
}

__global__ __launch_bounds__(TPB) void fine_count(
    const int2* __restrict__ ebuf, const int* __restrict__ bstart,
    const int* __restrict__ btot, int* __restrict__ cnt, int Nn)
{
    __shared__ int hist[TPB];
    hist[threadIdx.x] = 0;
    __syncthreads();
    const int b    = blockIdx.x;
    const int base = bstart[b];
    const int ne   = btot[b];
    const int nb0  = b << 8;
    for (int i = threadIdx.x; i < ne; i += TPB)
        atomicAdd(&hist[ebuf[base + i].y - nb0], 1);   // LDS atomic
    __syncthreads();
    int node = nb0 + threadIdx.x;
    if (node < Nn) cnt[node] = hist[threadIdx.x] + 1;
}

__global__ __launch_bounds__(TPB) void fine_scatter(
    const int2* __restrict__ ebuf, const int* __restrict__ bstart,
    const int* __restrict__ btot, const int* __restrict__ startp,
    int* __restrict__ adj)
{
    __shared__ int hist[TPB];
    hist[threadIdx.x] = 0;
    __syncthreads();
    const int b    = blockIdx.x;
    const int base = bstart[b];
    const int ne   = btot[b];
    const int nb0  = b << 8;
    for (int i = threadIdx.x; i < ne; i += TPB) {
        int2 e = ebuf[base + i];
        int lr = atomicAdd(&hist[e.y - nb0], 1);       // LDS atomic
        adj[startp[e.y] + 1 + lr] = e.x;
    }
}

// ---------------- node-level scan (cnt -> startp, self-loops) ---------------
__global__ void scan_block(const int* __restrict__ cnt, int* __restrict__ excl,
                           int* __restrict__ bsum, int n) {
    __shared__ int sm[SCAN_B];
    int i = blockIdx.x * SCAN_B + threadIdx.x;
    int v = (i < n) ? cnt[i] : 0;
    sm[threadIdx.x] = v;
    __syncthreads();
    for (int off = 1; off < SCAN_B; off <<= 1) {
        int t = (threadIdx.x >= off) ? sm[threadIdx.x - off] : 0;
        __syncthreads();
        sm[threadIdx.x] += t;
        __syncthreads();
    }
    if (i < n) excl[i] = sm[threadIdx.x] - v;
    if (threadIdx.x == SCAN_B - 1) bsum[blockIdx.x] = sm[threadIdx.x];
}

__global__ void scan_bsum(int* __restrict__ bsum, int nb) {   // one block, nb<=512
    __shared__ int sm[512];
    int v = (threadIdx.x < nb) ? bsum[threadIdx.x] : 0;
    sm[threadIdx.x] = v;
    __syncthreads();
    for (int off = 1; off < 512; off <<= 1) {
        int t = (threadIdx.x >= off) ? sm[threadIdx.x - off] : 0;
        __syncthreads();
        sm[threadIdx.x] += t;
        __syncthreads();
    }
    if (threadIdx.x < nb) bsum[threadIdx.x] = sm[threadIdx.x] - v;
}

__global__ void scan_add_self(int* __restrict__ excl, const int* __restrict__ bsum,
                              int* __restrict__ adj, int n) {
    int i = blockIdx.x * SCAN_B + threadIdx.x;
    if (i < n) {
        int s = excl[i] + bsum[blockIdx.x];
        excl[i] = s;          // excl becomes start
        adj[s]  = i;          // self-loop first in row
    }
}

__device__ __forceinline__ float4 f4z() { return make_float4(0.f, 0.f, 0.f, 0.f); }

// ---------------- MFMA GEMM (+ attention-dot epilogue) ----------------------
// asrc/adst written PRE-SCALED by log2(e) so agg_pass can use native exp2.
template<int NCOL, int H, int C>
__global__ __launch_bounds__(TPB) void gemm_att_k(
    const float* __restrict__ X,
    const ushort* __restrict__ Wfh, const ushort* __restrict__ Wfl,
    const float* __restrict__ att_src, const float* __restrict__ att_dst,
    ushort* __restrict__ Hout, float* __restrict__ asrc, float* __restrict__ adst,
    int Nrows)
{
    constexpr int CT  = NCOL / 16;     // col tiles (8 L1, 4 L2)
    constexpr int GRP = C / 16;        // col tiles per head (1 L1, 4 L2)
    constexpr int LSTR = 136;          // LDS row stride (shorts)

    __shared__ ushort Xh[64 * LSTR], Xl[64 * LSTR];

    const int tid  = threadIdx.x;
    const int row0 = blockIdx.x * 64;

    for (int idx = tid; idx < 64 * 32; idx += TPB) {
        int row = idx >> 5, c4 = idx & 31;
        int gr = row0 + row;
        float4 v = (gr < Nrows) ? ((const float4*)(X + (size_t)gr * 128))[c4] : f4z();
        ushort4 hh, ll;
        hh.x = bfr(v.x); hh.y = bfr(v.y); hh.z = bfr(v.z); hh.w = bfr(v.w);
        ll.x = bfr(v.x - ubf(hh.x)); ll.y = bfr(v.y - ubf(hh.y));
        ll.z = bfr(v.z - ubf(hh.z)); ll.w = bfr(v.w - ubf(hh.w));
        *(ushort4*)&Xh[row * LSTR + c4 * 4] = hh;
        *(ushort4*)&Xl[row * LSTR + c4 * 4] = ll;
    }
    __syncthreads();

    const int lane = tid & 63;
    const int wv   = tid >> 6;       // row tile
    const int lr   = lane & 15;      // A row / B,D col within tile
    const int lk   = lane >> 4;      // k subgroup

    f32x4 acc[CT];
#pragma unroll
    for (int ct = 0; ct < CT; ++ct) acc[ct] = (f32x4){0.f, 0.f, 0.f, 0.f};

#pragma unroll
    for (int kt = 0; kt < 4; ++kt) {
        bf16x8 ah = *(bf16x8*)&Xh[(wv * 16 + lr) * LSTR + kt * 32 + lk * 8];
        bf16x8 al = *(bf16x8*)&Xl[(wv * 16 + lr) * LSTR + kt * 32 + lk * 8];
        const int kb = (kt * 4 + lk) * NCOL;
#pragma unroll
        for (int ct = 0; ct < CT; ++ct) {
            bf16x8 bh = *(const bf16x8*)(Wfh + (size_t)(kb + ct * 16 + lr) * 8);
            bf16x8 bl = *(const bf16x8*)(Wfl + (size_t)(kb + ct * 16 + lr) * 8);
            acc[ct] = __builtin_amdgcn_mfma_f32_16x16x32_bf16(ah, bh, acc[ct], 0, 0, 0);
            acc[ct] = __builtin_amdgcn_mfma_f32_16x16x32_bf16(ah, bl, acc[ct], 0, 0, 0);
            acc[ct] = __builtin_amdgcn_mfma_f32_16x16x32_bf16(al, bh, acc[ct], 0, 0, 0);
        }
    }

    // ---- epilogue: h store (bf16) + per-head attention dots ----
    float asv[CT], adv[CT];
#pragma unroll
    for (int ct = 0; ct < CT; ++ct) {
        asv[ct] = att_src[ct * 16 + lr];   // (H,C) contiguous == flat col
        adv[ct] = att_dst[ct * 16 + lr];
    }

#pragma unroll
    for (int r = 0; r < 4; ++r) {
        const int n  = row0 + wv * 16 + lk * 4 + r;
        const bool ok = (n < Nrows);
        if (ok) {
#pragma unroll
            for (int ct = 0; ct < CT; ++ct)
                Hout[(size_t)n * NCOL + ct * 16 + lr] = bfr(acc[ct][r]);
        }
#pragma unroll
        for (int hg = 0; hg < CT / GRP; ++hg) {
            float ps = 0.f, pd = 0.f;
#pragma unroll
            for (int g = 0; g < GRP; ++g) {
                float a = acc[hg * GRP + g][r];
                ps += a * asv[hg * GRP + g];
                pd += a * adv[hg * GRP + g];
            }
#pragma unroll
            for (int s = 1; s < 16; s <<= 1) {
                ps += __shfl_xor(ps, s, 64);
                pd += __shfl_xor(pd, s, 64);
            }
            if (ok && lr == 0) {
                asrc[(size_t)n * H + hg] = ps * LOG2E;
                adst[(size_t)n * H + hg] = pd * LOG2E;
            }
        }
    }
}

// ---------------- fused aggregation (uint2, sentinel, exp2) -----------------
// One wave per node.  lane = (eg, cg): cg = lane%LPR column chunk (uint2 =
// 4 bf16 cols), eg = edge slot.  Out-of-range lanes use sentinel node Nn
// (asrc[Nn] = -1e30 -> pj = 0): inner loop has NO guards.
template<int H, int C, bool DOELU>
__global__ __launch_bounds__(TPB) void agg_pass(
    const ushort* __restrict__ Hf, const int* __restrict__ adj,
    const int* __restrict__ cnt, const int* __restrict__ start,
    const float* __restrict__ asrc, const float* __restrict__ adst,
    const float* __restrict__ bias, float* __restrict__ out, int Nn)
{
    constexpr int F   = H * C;
    constexpr int LPR = F / 4;      // lanes per row (32 L1, 16 L2)
    constexpr int EPL = 64 / LPR;   // edges per wave-load (2 L1, 4 L2)
    constexpr int GQ  = 4;          // load-units in flight

    const int lane = threadIdx.x & 63;
    const int d    = blockIdx.x * (TPB / 64) + (threadIdx.x >> 6);
    if (d >= Nn) return;

    const int eg = lane / LPR;
    const int cg = lane % LPR;
    const int hc = (cg * 4) / C;    // head of this lane's columns

    const float adstv = adst[(size_t)d * H + hc];

    float acc[4] = {0.f, 0.f, 0.f, 0.f};
    float den = 0.f;

    const int ne = cnt[d];
    const int rs = start[d];

    for (int b = 0; b < ne; b += 64) {
        const int kn = min(64, ne - b);
        int sj = (lane < kn) ? adj[rs + b + lane] : Nn;   // sentinel pad

        for (int g = 0; g * (GQ * EPL) < kn; ++g) {
            uint2 wv[GQ];
            float av[GQ];
#pragma unroll
            for (int qi = 0; qi < GQ; ++qi) {
                int j  = (g * GQ + qi) * EPL + eg;
                int sv = __shfl(sj, j, 64);
                wv[qi] = *(const uint2*)(Hf + (size_t)sv * F + cg * 4);
                av[qi] = asrc[(size_t)sv * H + hc];
            }
#pragma unroll
            for (int qi = 0; qi < GQ; ++qi) {
                float t = av[qi] + adstv;           // log2-domain score
                t = fmaxf(t, 0.2f * t);             // leaky (max form)
                float pj = exp2f(t);                // native v_exp_f32
                den += pj;
                acc[0] += pj * ubf((ushort)(wv[qi].x & 0xffffu));
                acc[1] += pj * ubf((ushort)(wv[qi].x >> 16));
                acc[2] += pj * ubf((ushort)(wv[qi].y & 0xffffu));
                acc[3] += pj * ubf((ushort)(wv[qi].y >> 16));
            }
        }
    }

    // fold edge slots (lanes differing in eg share cg / head)
#pragma unroll
    for (int s = LPR; s < 64; s <<= 1) {
        den += __shfl_xor(den, s, 64);
#pragma unroll
        for (int c = 0; c < 4; ++c) acc[c] += __shfl_xor(acc[c], s, 64);
    }

    if (eg == 0) {
        const float invd = 1.0f / (den + 1e-16f);
        float4 o;
        float* oc = (float*)&o;
#pragma unroll
        for (int c = 0; c < 4; ++c) {
            float t = acc[c] * invd + bias[cg * 4 + c];
            if (DOELU) t = t > 0.f ? t : expm1f(t);
            oc[c] = t;
        }
        *(float4*)(out + (size_t)d * F + cg * 4) = o;
    }
}

static inline unsigned nblk(long long tot) { return (unsigned)((tot + TPB - 1) / TPB); }

extern "C" void kernel_launch(void* const* d_in, const int* in_sizes, int n_in,
                              void* d_out, int out_size, void* d_ws, size_t ws_size,
                              hipStream_t stream)
{
    const float* x   = (const float*)d_in[0];
    const int*   ei  = (const int*)d_in[1];   // int32 or int64 (detected)
    const float* W1  = (const float*)d_in[2];
    const float* as1 = (const float*)d_in[3];
    const float* ad1 = (const float*)d_in[4];
    const float* b1  = (const float*)d_in[5];
    const float* W2  = (const float*)d_in[6];
    const float* as2 = (const float*)d_in[7];
    const float* ad2 = (const float*)d_in[8];
    const float* b2  = (const float*)d_in[9];
    float* out = (float*)d_out;

    const int Nn  = in_sizes[0] / 128;   // 100000
    const int E   = in_sizes[1] / 2;     // 1600000
    const int ET  = E + Nn;              // edges incl self-loops
    const int NB1 = (Nn + 255) / 256;    // coarse buckets (391)
    const int GBE = (E + 1023) / 1024;   // edge blocks (1563)

    // workspace layout (float units)
    float*  ws    = (float*)d_ws;
    ushort* h1b   = (ushort*)ws;                       // 128*(N+1) bf16 (sentinel row)
    float*  helu  = (float*)(h1b + (size_t)128 * (Nn + 1));  // 128N f32
    float*  asrc2 = helu + (size_t)128 * Nn;           // N+1 (sentinel)
    float*  adst2 = asrc2 + Nn + 1;                    // N
    ushort* w1h   = (ushort*)(adst2 + Nn);             // 16384
    ushort* w1l   = w1h + 16384;                       // 16384
    ushort* w2h   = w1l + 16384;                       // 8192
    ushort* w2l   = w2h + 8192;                        // 8192
    int*    cnt   = (int*)(w2l + 8192);                // N
    int*    startp= cnt + Nn;                          // N
    int*    bsum  = startp + Nn;                       // 512
    int*    adj   = bsum + 512;                        // ET + pad
    int*    bh    = adj + ET + 64;                     // GBE*NB1 (~611K)
    int*    btot  = bh + (size_t)GBE * NB1;            // 512
    int*    bstart= btot + 512;                        // 512
    int*    flag  = bstart + 512;                      // 1 (+pad to even)
    int2*   ebuf  = (int2*)(flag + 3);                 // E int2
    ushort* h2b   = h1b;                               // 64*(N+1) bf16 (L2 reuse)
    // layer-1 attention scores live in d_out (dead before final write)
    float*  asrc1 = out;                               // 8*(N+1)
    float*  adst1 = asrc1 + (size_t)8 * (Nn + 1);      // 8N

    const int NB = (Nn + SCAN_B - 1) / SCAN_B;         // 391 <= 512
    const int GB = (Nn + 63) / 64;                     // gemm blocks (1563)

    detect_idx64<<<1, 64, 0, stream>>>((const unsigned*)ei, flag);
    convert_W<<<64, TPB, 0, stream>>>(W1, w1h, w1l, 128 * 128, 128);
    convert_W<<<32, TPB, 0, stream>>>(W2, w2h, w2l, 128 * 64, 64);
    set_sentinels<<<1, 64, 0, stream>>>(asrc1, asrc2, Nn);

    // ---- CSR build: two-level bucketing, zero global atomics ----
    hist_coarse<<<GBE, TPB, 0, stream>>>(ei, flag, E, NB1, bh);
    scan_bh<<<NB1, TPB, 0, stream>>>(bh, GBE, NB1, btot);
    scan_btot<<<1, 512, 0, stream>>>(btot, bstart, NB1);
    scatter_coarse<<<GBE, TPB, 0, stream>>>(ei, flag, E, NB1, bh, bstart, ebuf);
    fine_count<<<NB1, TPB, 0, stream>>>(ebuf, bstart, btot, cnt, Nn);
    scan_block<<<NB, SCAN_B, 0, stream>>>(cnt, startp, bsum, Nn);
    scan_bsum<<<1, 512, 0, stream>>>(bsum, NB);
    scan_add_self<<<NB, SCAN_B, 0, stream>>>(startp, bsum, adj, Nn);
    fine_scatter<<<NB1, TPB, 0, stream>>>(ebuf, bstart, btot, startp, adj);

    // ---- layer 1 ----
    gemm_att_k<128, 8, 16><<<GB, TPB, 0, stream>>>(
        x, w1h, w1l, as1, ad1, h1b, asrc1, adst1, Nn);
    agg_pass<8, 16, true><<<(Nn + 3) / 4, TPB, 0, stream>>>(
        h1b, adj, cnt, startp, asrc1, adst1, b1, helu, Nn);

    // ---- layer 2 ----
    gemm_att_k<64, 1, 64><<<GB, TPB, 0, stream>>>(
        helu, w2h, w2l, as2, ad2, h2b, asrc2, adst2, Nn);
    agg_pass<1, 64, false><<<(Nn + 3) / 4, TPB, 0, stream>>>(
        h2b, adj, cnt, startp, asrc2, adst2, b2, out, Nn);
}

// Round 16
// 265.010 us; speedup vs baseline: 1.1206x; 1.0720x over previous
//
#include <hip/hip_runtime.h>
#include <hip/hip_bf16.h>
#include <math.h>

// ---------------------------------------------------------------------------
// GAT 2-layer forward.  N=100000 nodes, E=1.6M edges, self-loops in CSR.
// L1: 128 -> H=8,C=16 ; L2: 128 -> H=1,C=64.
// GEMMs on MFMA 16x16x32 bf16, split-bf16 (hi+lo, 3 mfma) ~f32 accuracy.
// CSR: zero global atomics.  Coarse histogram FUSED into GEMM1 (LDS hist);
// fine level = ONE kernel per bucket (count + local scan + scatter), since
// gstart[b] = bstart[b] + 256*b makes the global node-scan unnecessary.
// agg_pass: uint2 gathers, sentinel padding, exp2(log2e-prescaled scores).
// ---------------------------------------------------------------------------

#define TPB 256
#define LOG2E 1.44269504088896f

typedef unsigned int uint;
typedef unsigned short ushort;
typedef short bf16x8 __attribute__((ext_vector_type(8)));
typedef float f32x4 __attribute__((ext_vector_type(4)));

__device__ __forceinline__ ushort bfr(float x) {          // f32 -> bf16 RTNE
    uint u = __float_as_uint(x);
    return (ushort)((u + 0x7fffu + ((u >> 16) & 1u)) >> 16);
}
__device__ __forceinline__ float ubf(ushort s) {          // bf16 -> f32
    return __uint_as_float((uint)s << 16);
}

// ---------------- setup: W conversion + idx64 detect + sentinels ------------
// W[k][col] f32 -> frag-ready hi/lo bf16 at [(k/8)*NCOL + col][k%8]
__device__ __forceinline__ void convW(const float* W, ushort* Wfh, ushort* Wfl,
                                      int i, int NCOL) {
    int k = i / NCOL, col = i % NCOL;
    float w = W[i];
    ushort hh = bfr(w);
    float lo = w - ubf(hh);
    int o = ((k >> 3) * NCOL + col) * 8 + (k & 7);
    Wfh[o] = hh;
    Wfl[o] = bfr(lo);
}

__global__ void setup(const float* __restrict__ W1, ushort* __restrict__ w1h,
                      ushort* __restrict__ w1l,
                      const float* __restrict__ W2, ushort* __restrict__ w2h,
                      ushort* __restrict__ w2l,
                      const unsigned* __restrict__ ei, int* __restrict__ flag,
                      float* __restrict__ asrc1, float* __restrict__ asrc2, int Nn)
{
    int i = blockIdx.x * TPB + threadIdx.x;
    if (i < 16384) {
        convW(W1, w1h, w1l, i, 128);
    } else if (i < 24576) {
        convW(W2, w2h, w2l, i - 16384, 64);
    } else if (i < 24640) {           // one full wave: idx64 detect
        unsigned v = ei[(size_t)(i - 24576) * 2 + 1];
        unsigned long long b = __ballot(v != 0u);
        if (i == 24576) *flag = (b == 0ull) ? 1 : 0;
    } else if (i < 24648) {           // sentinel scores (node Nn)
        asrc1[(size_t)8 * Nn + (i - 24640)] = -1e30f;
    } else if (i == 24648) {
        asrc2[Nn] = -1e30f;
    }
}

// ---------------- CSR build ----------------
// per-bucket exclusive scan across blocks (in place); btot[bin] = total
__global__ __launch_bounds__(TPB) void scan_bh(
    int* __restrict__ bh, int gbe, int nb1, int* __restrict__ btot)
{
    __shared__ int sm[TPB];
    const int bin = blockIdx.x;
    int running = 0;
    for (int c0 = 0; c0 < gbe; c0 += TPB) {
        int idx = c0 + threadIdx.x;
        int v = (idx < gbe) ? bh[(size_t)idx * nb1 + bin] : 0;
        sm[threadIdx.x] = v;
        __syncthreads();
        for (int off = 1; off < TPB; off <<= 1) {
            int t = (threadIdx.x >= off) ? sm[threadIdx.x - off] : 0;
            __syncthreads();
            sm[threadIdx.x] += t;
            __syncthreads();
        }
        if (idx < gbe) bh[(size_t)idx * nb1 + bin] = running + sm[threadIdx.x] - v;
        int ctot = sm[TPB - 1];
        __syncthreads();
        running += ctot;
    }
    if (threadIdx.x == 0) btot[bin] = running;
}

__global__ void scan_btot(const int* __restrict__ btot, int* __restrict__ bstart, int nb) {
    __shared__ int sm[512];
    int v = (threadIdx.x < nb) ? btot[threadIdx.x] : 0;
    sm[threadIdx.x] = v;
    __syncthreads();
    for (int off = 1; off < 512; off <<= 1) {
        int t = (threadIdx.x >= off) ? sm[threadIdx.x - off] : 0;
        __syncthreads();
        sm[threadIdx.x] += t;
        __syncthreads();
    }
    if (threadIdx.x < nb) bstart[threadIdx.x] = sm[threadIdx.x] - v;
}

// scatter edges into coarse-bucket-contiguous ebuf (LDS atomics only)
__global__ __launch_bounds__(TPB) void scatter_coarse(
    const int* __restrict__ ei, const int* __restrict__ shiftp, int E, int nb1,
    const int* __restrict__ bh, const int* __restrict__ bstart,
    int2* __restrict__ ebuf)
{
    __shared__ int hist[512];
    for (int i = threadIdx.x; i < nb1; i += TPB) hist[i] = 0;
    __syncthreads();
    const int sh = *shiftp;
    const int e0 = blockIdx.x * (TPB * 4) + threadIdx.x;
#pragma unroll
    for (int k = 0; k < 4; ++k) {
        int e = e0 + k * TPB;
        if (e < E) {
            int s = ei[(size_t)e << sh];
            int d = ei[((size_t)E + e) << sh];
            int bin = d >> 8;
            int lr = atomicAdd(&hist[bin], 1);     // LDS atomic
            int pos = bstart[bin] + bh[(size_t)blockIdx.x * nb1 + bin] + lr;
            ebuf[pos] = make_int2(s, d);
        }
    }
}

// ONE kernel per bucket: fine count + local scan + startp/cnt/self-loop/adj.
// adj base for bucket b = bstart[b] + (b<<8)  (self-loop slot per node).
__global__ __launch_bounds__(TPB) void fine_build(
    const int2* __restrict__ ebuf, const int* __restrict__ bstart,
    const int* __restrict__ btot, int* __restrict__ cnt,
    int* __restrict__ startp, int* __restrict__ adj, int Nn)
{
    __shared__ int hist[TPB];
    __shared__ int sm[TPB];
    __shared__ int cur[TPB];
    const int tid  = threadIdx.x;
    const int b    = blockIdx.x;
    const int base = bstart[b];
    const int ne   = btot[b];
    const int nb0  = b << 8;

    hist[tid] = 0;
    __syncthreads();
    for (int i = tid; i < ne; i += TPB)
        atomicAdd(&hist[ebuf[base + i].y - nb0], 1);   // LDS atomic
    __syncthreads();

    // exclusive scan of hist (256 bins)
    int v = hist[tid];
    sm[tid] = v;
    __syncthreads();
    for (int off = 1; off < TPB; off <<= 1) {
        int t = (tid >= off) ? sm[tid - off] : 0;
        __syncthreads();
        sm[tid] += t;
        __syncthreads();
    }
    const int excl = sm[tid] - v;
    const int st   = base + nb0 + excl + tid;   // adj position of self-loop
    const int node = nb0 + tid;
    if (node < Nn) {
        startp[node] = st;
        cnt[node]    = v + 1;
        adj[st]      = node;                    // self-loop first in row
    }
    cur[tid] = st + 1;
    __syncthreads();
    for (int i = tid; i < ne; i += TPB) {
        int2 e = ebuf[base + i];
        int lr = atomicAdd(&cur[e.y - nb0], 1); // LDS atomic
        adj[lr] = e.x;
    }
}

__device__ __forceinline__ float4 f4z() { return make_float4(0.f, 0.f, 0.f, 0.f); }

// ---------------- MFMA GEMM (+ attention epilogue, optional coarse hist) ----
// asrc/adst written PRE-SCALED by log2(e) so agg_pass can use native exp2.
// HIST: per-block LDS histogram of edge dst>>8 -> bh[blk][nb1] (no atomics
// on global, no return values; hides the edge pass under the GEMM).
template<int NCOL, int H, int C, bool HIST>
__global__ __launch_bounds__(TPB) void gemm_att_k(
    const float* __restrict__ X,
    const ushort* __restrict__ Wfh, const ushort* __restrict__ Wfl,
    const float* __restrict__ att_src, const float* __restrict__ att_dst,
    ushort* __restrict__ Hout, float* __restrict__ asrc, float* __restrict__ adst,
    int Nrows,
    const int* __restrict__ ei, const int* __restrict__ shiftp, int E, int nb1,
    int* __restrict__ bh)
{
    constexpr int CT  = NCOL / 16;     // col tiles (8 L1, 4 L2)
    constexpr int GRP = C / 16;        // col tiles per head (1 L1, 4 L2)
    constexpr int LSTR = 136;          // LDS row stride (shorts)

    __shared__ ushort Xh[64 * LSTR], Xl[64 * LSTR];
    __shared__ int hist[512];

    const int tid  = threadIdx.x;
    const int row0 = blockIdx.x * 64;

    int dvals[4];
    if constexpr (HIST) {
        const int sh = *shiftp;
        const int e0 = blockIdx.x * (TPB * 4) + tid;
#pragma unroll
        for (int k = 0; k < 4; ++k) {
            int e = e0 + k * TPB;
            dvals[k] = (e < E) ? ei[((size_t)E + e) << sh] : -1;
        }
        for (int i = tid; i < nb1; i += TPB) hist[i] = 0;
    }

    // ---- stage X tile as hi/lo bf16 ----
    for (int idx = tid; idx < 64 * 32; idx += TPB) {
        int row = idx >> 5, c4 = idx & 31;
        int gr = row0 + row;
        float4 v = (gr < Nrows) ? ((const float4*)(X + (size_t)gr * 128))[c4] : f4z();
        ushort4 hh, ll;
        hh.x = bfr(v.x); hh.y = bfr(v.y); hh.z = bfr(v.z); hh.w = bfr(v.w);
        ll.x = bfr(v.x - ubf(hh.x)); ll.y = bfr(v.y - ubf(hh.y));
        ll.z = bfr(v.z - ubf(hh.z)); ll.w = bfr(v.w - ubf(hh.w));
        *(ushort4*)&Xh[row * LSTR + c4 * 4] = hh;
        *(ushort4*)&Xl[row * LSTR + c4 * 4] = ll;
    }
    __syncthreads();

    if constexpr (HIST) {
#pragma unroll
        for (int k = 0; k < 4; ++k)
            if (dvals[k] >= 0) atomicAdd(&hist[dvals[k] >> 8], 1);  // LDS atomic
    }

    const int lane = tid & 63;
    const int wv   = tid >> 6;       // row tile
    const int lr   = lane & 15;      // A row / B,D col within tile
    const int lk   = lane >> 4;      // k subgroup

    f32x4 acc[CT];
#pragma unroll
    for (int ct = 0; ct < CT; ++ct) acc[ct] = (f32x4){0.f, 0.f, 0.f, 0.f};

#pragma unroll
    for (int kt = 0; kt < 4; ++kt) {
        bf16x8 ah = *(bf16x8*)&Xh[(wv * 16 + lr) * LSTR + kt * 32 + lk * 8];
        bf16x8 al = *(bf16x8*)&Xl[(wv * 16 + lr) * LSTR + kt * 32 + lk * 8];
        const int kb = (kt * 4 + lk) * NCOL;
#pragma unroll
        for (int ct = 0; ct < CT; ++ct) {
            bf16x8 bh_ = *(const bf16x8*)(Wfh + (size_t)(kb + ct * 16 + lr) * 8);
            bf16x8 bl_ = *(const bf16x8*)(Wfl + (size_t)(kb + ct * 16 + lr) * 8);
            acc[ct] = __builtin_amdgcn_mfma_f32_16x16x32_bf16(ah, bh_, acc[ct], 0, 0, 0);
            acc[ct] = __builtin_amdgcn_mfma_f32_16x16x32_bf16(ah, bl_, acc[ct], 0, 0, 0);
            acc[ct] = __builtin_amdgcn_mfma_f32_16x16x32_bf16(al, bh_, acc[ct], 0, 0, 0);
        }
    }

    // ---- epilogue: h store (bf16) + per-head attention dots ----
    float asv[CT], adv[CT];
#pragma unroll
    for (int ct = 0; ct < CT; ++ct) {
        asv[ct] = att_src[ct * 16 + lr];   // (H,C) contiguous == flat col
        adv[ct] = att_dst[ct * 16 + lr];
    }

#pragma unroll
    for (int r = 0; r < 4; ++r) {
        const int n  = row0 + wv * 16 + lk * 4 + r;
        const bool ok = (n < Nrows);
        if (ok) {
#pragma unroll
            for (int ct = 0; ct < CT; ++ct)
                Hout[(size_t)n * NCOL + ct * 16 + lr] = bfr(acc[ct][r]);
        }
#pragma unroll
        for (int hg = 0; hg < CT / GRP; ++hg) {
            float ps = 0.f, pd = 0.f;
#pragma unroll
            for (int g = 0; g < GRP; ++g) {
                float a = acc[hg * GRP + g][r];
                ps += a * asv[hg * GRP + g];
                pd += a * adv[hg * GRP + g];
            }
#pragma unroll
            for (int s = 1; s < 16; s <<= 1) {
                ps += __shfl_xor(ps, s, 64);
                pd += __shfl_xor(pd, s, 64);
            }
            if (ok && lr == 0) {
                asrc[(size_t)n * H + hg] = ps * LOG2E;
                adst[(size_t)n * H + hg] = pd * LOG2E;
            }
        }
    }

    if constexpr (HIST) {
        __syncthreads();
        for (int i = tid; i < nb1; i += TPB)
            bh[(size_t)blockIdx.x * nb1 + i] = hist[i];
    }
}

// ---------------- fused aggregation (uint2, sentinel, exp2) -----------------
template<int H, int C, bool DOELU>
__global__ __launch_bounds__(TPB) void agg_pass(
    const ushort* __restrict__ Hf, const int* __restrict__ adj,
    const int* __restrict__ cnt, const int* __restrict__ start,
    const float* __restrict__ asrc, const float* __restrict__ adst,
    const float* __restrict__ bias, float* __restrict__ out, int Nn)
{
    constexpr int F   = H * C;
    constexpr int LPR = F / 4;      // lanes per row (32 L1, 16 L2)
    constexpr int EPL = 64 / LPR;   // edges per wave-load (2 L1, 4 L2)
    constexpr int GQ  = 4;          // load-units in flight

    const int lane = threadIdx.x & 63;
    const int d    = blockIdx.x * (TPB / 64) + (threadIdx.x >> 6);
    if (d >= Nn) return;

    const int eg = lane / LPR;
    const int cg = lane % LPR;
    const int hc = (cg * 4) / C;    // head of this lane's columns

    const float adstv = adst[(size_t)d * H + hc];

    float acc[4] = {0.f, 0.f, 0.f, 0.f};
    float den = 0.f;

    const int ne = cnt[d];
    const int rs = start[d];

    for (int b = 0; b < ne; b += 64) {
        const int kn = min(64, ne - b);
        int sj = (lane < kn) ? adj[rs + b + lane] : Nn;   // sentinel pad

        for (int g = 0; g * (GQ * EPL) < kn; ++g) {
            uint2 wv[GQ];
            float av[GQ];
#pragma unroll
            for (int qi = 0; qi < GQ; ++qi) {
                int j  = (g * GQ + qi) * EPL + eg;
                int sv = __shfl(sj, j, 64);
                wv[qi] = *(const uint2*)(Hf + (size_t)sv * F + cg * 4);
                av[qi] = asrc[(size_t)sv * H + hc];
            }
#pragma unroll
            for (int qi = 0; qi < GQ; ++qi) {
                float t = av[qi] + adstv;           // log2-domain score
                t = fmaxf(t, 0.2f * t);             // leaky (max form)
                float pj = exp2f(t);                // native v_exp_f32
                den += pj;
                acc[0] += pj * ubf((ushort)(wv[qi].x & 0xffffu));
                acc[1] += pj * ubf((ushort)(wv[qi].x >> 16));
                acc[2] += pj * ubf((ushort)(wv[qi].y & 0xffffu));
                acc[3] += pj * ubf((ushort)(wv[qi].y >> 16));
            }
        }
    }

    // fold edge slots (lanes differing in eg share cg / head)
#pragma unroll
    for (int s = LPR; s < 64; s <<= 1) {
        den += __shfl_xor(den, s, 64);
#pragma unroll
        for (int c = 0; c < 4; ++c) acc[c] += __shfl_xor(acc[c], s, 64);
    }

    if (eg == 0) {
        const float invd = 1.0f / (den + 1e-16f);
        float4 o;
        float* oc = (float*)&o;
#pragma unroll
        for (int c = 0; c < 4; ++c) {
            float t = acc[c] * invd + bias[cg * 4 + c];
            if (DOELU) t = t > 0.f ? t : expm1f(t);
            oc[c] = t;
        }
        *(float4*)(out + (size_t)d * F + cg * 4) = o;
    }
}

static inline unsigned nblk(long long tot) { return (unsigned)((tot + TPB - 1) / TPB); }

extern "C" void kernel_launch(void* const* d_in, const int* in_sizes, int n_in,
                              void* d_out, int out_size, void* d_ws, size_t ws_size,
                              hipStream_t stream)
{
    const float* x   = (const float*)d_in[0];
    const int*   ei  = (const int*)d_in[1];   // int32 or int64 (detected)
    const float* W1  = (const float*)d_in[2];
    const float* as1 = (const float*)d_in[3];
    const float* ad1 = (const float*)d_in[4];
    const float* b1  = (const float*)d_in[5];
    const float* W2  = (const float*)d_in[6];
    const float* as2 = (const float*)d_in[7];
    const float* ad2 = (const float*)d_in[8];
    const float* b2  = (const float*)d_in[9];
    float* out = (float*)d_out;

    const int Nn  = in_sizes[0] / 128;   // 100000
    const int E   = in_sizes[1] / 2;     // 1600000
    const int ET  = E + Nn;              // edges incl self-loops
    const int NB1 = (Nn + 255) / 256;    // coarse buckets (391)
    const int GB  = (Nn + 63) / 64;      // gemm blocks (1563)
    const int GBE = (E + 1023) / 1024;   // edge blocks (1563)
    const int GBM = (GB > GBE) ? GB : GBE;

    // workspace layout (float units)
    float*  ws    = (float*)d_ws;
    ushort* h1b   = (ushort*)ws;                       // 128*(N+1) bf16 (sentinel row)
    float*  helu  = (float*)(h1b + (size_t)128 * (Nn + 1));  // 128N f32
    float*  asrc2 = helu + (size_t)128 * Nn;           // N+1 (sentinel)
    float*  adst2 = asrc2 + Nn + 1;                    // N
    ushort* w1h   = (ushort*)(adst2 + Nn);             // 16384
    ushort* w1l   = w1h + 16384;                       // 16384
    ushort* w2h   = w1l + 16384;                       // 8192
    ushort* w2l   = w2h + 8192;                        // 8192
    int*    cnt   = (int*)(w2l + 8192);                // N
    int*    startp= cnt + Nn;                          // N
    int*    adj   = startp + Nn;                       // ET + pad
    int*    bh    = adj + ET + 64;                     // GBM*NB1 (~611K)
    int*    btot  = bh + (size_t)GBM * NB1;            // 512
    int*    bstart= btot + 512;                        // 512
    int*    flag  = bstart + 512;                      // 1 (+pad to even)
    int2*   ebuf  = (int2*)(flag + 3);                 // E int2
    ushort* h2b   = h1b;                               // 64*(N+1) bf16 (L2 reuse)
    // layer-1 attention scores live in d_out (dead before final write)
    float*  asrc1 = out;                               // 8*(N+1)
    float*  adst1 = asrc1 + (size_t)8 * (Nn + 1);      // 8N

    // ---- setup: W conversion + idx64 detect + sentinels (one kernel) ----
    setup<<<97, TPB, 0, stream>>>((const float*)W1, w1h, w1l,
                                  (const float*)W2, w2h, w2l,
                                  (const unsigned*)ei, flag, asrc1, asrc2, Nn);

    // ---- layer-1 GEMM (MFMA) fused with coarse CSR histogram ----
    gemm_att_k<128, 8, 16, true><<<GBM, TPB, 0, stream>>>(
        x, w1h, w1l, as1, ad1, h1b, asrc1, adst1, Nn, ei, flag, E, NB1, bh);

    // ---- CSR: scans + coarse scatter + fused fine build ----
    scan_bh<<<NB1, TPB, 0, stream>>>(bh, GBM, NB1, btot);
    scan_btot<<<1, 512, 0, stream>>>(btot, bstart, NB1);
    scatter_coarse<<<GBE, TPB, 0, stream>>>(ei, flag, E, NB1, bh, bstart, ebuf);
    fine_build<<<NB1, TPB, 0, stream>>>(ebuf, bstart, btot, cnt, startp, adj, Nn);

    // ---- layer 1 aggregation ----
    agg_pass<8, 16, true><<<(Nn + 3) / 4, TPB, 0, stream>>>(
        h1b, adj, cnt, startp, asrc1, adst1, b1, helu, Nn);

    // ---- layer 2 ----
    gemm_att_k<64, 1, 64, false><<<GB, TPB, 0, stream>>>(
        helu, w2h, w2l, as2, ad2, h2b, asrc2, adst2, Nn,
        nullptr, nullptr, 0, 0, nullptr);
    agg_pass<1, 64, false><<<(Nn + 3) / 4, TPB, 0, stream>>>(
        h2b, adj, cnt, startp, asrc2, adst2, b2, out, Nn);
}